// Round 5
// baseline (402.790 us; speedup 1.0000x reference)
//
#include <hip/hip_runtime.h>

typedef __bf16 bf16;
typedef __bf16 bf16x8 __attribute__((ext_vector_type(8)));
typedef float  f32x4  __attribute__((ext_vector_type(4)));

static constexpr int CB = 2;     // batch
static constexpr int CS = 2048;  // seq
static constexpr int CD = 512;   // model dim
static constexpr int CH = 8;     // heads
static constexpr int CDK = 64;   // head dim
static constexpr int NROWS = CB * CH * CS;         // 32768 attention rows
static constexpr size_t NT = (size_t)CB * CS * CD; // 2,097,152 elements per tensor

__device__ __forceinline__ f32x4 mfma16(bf16x8 a, bf16x8 b, f32x4 c) {
    return __builtin_amdgcn_mfma_f32_16x16x32_bf16(a, b, c, 0, 0, 0);
}

__device__ __forceinline__ bf16x8 cvt8(const float* __restrict__ p) {
    float4 x0 = *reinterpret_cast<const float4*>(p);
    float4 x1 = *reinterpret_cast<const float4*>(p + 4);
    bf16x8 r;
    r[0] = (bf16)x0.x; r[1] = (bf16)x0.y; r[2] = (bf16)x0.z; r[3] = (bf16)x0.w;
    r[4] = (bf16)x1.x; r[5] = (bf16)x1.y; r[6] = (bf16)x1.z; r[7] = (bf16)x1.w;
    return r;
}

__device__ __forceinline__ void gload16(const void* g, void* l) {
    __builtin_amdgcn_global_load_lds(
        (const __attribute__((address_space(1))) void*)g,
        (__attribute__((address_space(3))) void*)l, 16, 0, 0);
}

struct PPtrs {
    const float* A[6];
    const float* W[6];
    const float* bias[6];
    bf16* dst[6];
    int mode[6];   // 0: [B,H,S,DK]   1: [B,H,DK,S] (transposed V)
};

// ---- merged projection GEMM, 128x128 tile: C[m,n] = sum_k A[m,k]*W[n,k] + bias[n] ----
__global__ __launch_bounds__(256) void proj_kernel(PPtrs P) {
    __shared__ bf16 aL[128][72];
    __shared__ bf16 bL[128][72];
    const int z = blockIdx.z;
    const float* __restrict__ A    = P.A[z];
    const float* __restrict__ Bt   = P.W[z];
    const float* __restrict__ bias = P.bias[z];
    bf16* __restrict__ dst = P.dst[z];
    const int mode = P.mode[z];

    const int m0 = blockIdx.x * 128, n0 = blockIdx.y * 128;
    const int tid = threadIdx.x;
    const int lane = tid & 63, w = tid >> 6;
    const int wr = w >> 1, wc = w & 1;
    const int l16 = lane & 15, lhi = lane >> 4;
    const int srow = tid >> 1, sk = (tid & 1) * 32;

    f32x4 acc[4][4] = {};

    for (int k0 = 0; k0 < 512; k0 += 64) {
        __syncthreads();
        #pragma unroll
        for (int c = 0; c < 4; ++c) {
            *reinterpret_cast<bf16x8*>(&aL[srow][sk + c*8]) =
                cvt8(A + (size_t)(m0 + srow) * 512 + k0 + sk + c*8);
            *reinterpret_cast<bf16x8*>(&bL[srow][sk + c*8]) =
                cvt8(Bt + (size_t)(n0 + srow) * 512 + k0 + sk + c*8);
        }
        __syncthreads();

        #pragma unroll
        for (int ks = 0; ks < 2; ++ks) {
            bf16x8 af[4], bg[4];
            #pragma unroll
            for (int ms = 0; ms < 4; ++ms)
                af[ms] = *reinterpret_cast<const bf16x8*>(&aL[wr*64 + ms*16 + l16][ks*32 + lhi*8]);
            #pragma unroll
            for (int ns = 0; ns < 4; ++ns)
                bg[ns] = *reinterpret_cast<const bf16x8*>(&bL[wc*64 + ns*16 + l16][ks*32 + lhi*8]);
            #pragma unroll
            for (int ms = 0; ms < 4; ++ms)
                #pragma unroll
                for (int ns = 0; ns < 4; ++ns)
                    acc[ms][ns] = mfma16(af[ms], bg[ns], acc[ms][ns]);
        }
    }

    #pragma unroll
    for (int ms = 0; ms < 4; ++ms)
    #pragma unroll
    for (int ns = 0; ns < 4; ++ns) {
        const int col = n0 + wc*64 + ns*16 + l16;
        const float bv = bias[col];
        const int hh = col >> 6, dk = col & 63;
        #pragma unroll
        for (int i = 0; i < 4; ++i) {
            const int m = m0 + wr*64 + ms*16 + lhi*4 + i;
            const float v = acc[ms][ns][i] + bv;
            const int b = m >> 11, s = m & 2047;
            if (mode == 0)
                dst[(((size_t)(b*CH + hh)) * CS + s) * CDK + dk] = (bf16)v;
            else
                dst[(((size_t)(b*CH + hh)) * CDK + dk) * CS + s] = (bf16)v;
        }
    }
}

// ---- output GEMM, 128x128 tile ----
__global__ __launch_bounds__(256) void oproj_kernel(
    const bf16* __restrict__ Xr, const bf16* __restrict__ Xp,
    const float* __restrict__ Wo, const float* __restrict__ bo,
    float* __restrict__ out)
{
    __shared__ bf16 aL[128][72];
    __shared__ bf16 bL[128][72];
    const bf16* __restrict__ A = blockIdx.z ? Xp : Xr;
    float* __restrict__ dst = out + (size_t)blockIdx.z * NT;

    const int m0 = blockIdx.x * 128, n0 = blockIdx.y * 128;
    const int tid = threadIdx.x;
    const int lane = tid & 63, w = tid >> 6;
    const int wr = w >> 1, wc = w & 1;
    const int l16 = lane & 15, lhi = lane >> 4;
    const int srow = tid >> 1, sk = (tid & 1) * 32;

    f32x4 acc[4][4] = {};

    for (int k0 = 0; k0 < 512; k0 += 64) {
        __syncthreads();
        #pragma unroll
        for (int c = 0; c < 4; ++c) {
            *reinterpret_cast<bf16x8*>(&aL[srow][sk + c*8]) =
                *reinterpret_cast<const bf16x8*>(A + (size_t)(m0 + srow) * 512 + k0 + sk + c*8);
            *reinterpret_cast<bf16x8*>(&bL[srow][sk + c*8]) =
                cvt8(Wo + (size_t)(n0 + srow) * 512 + k0 + sk + c*8);
        }
        __syncthreads();

        #pragma unroll
        for (int ks = 0; ks < 2; ++ks) {
            bf16x8 af[4], bg[4];
            #pragma unroll
            for (int ms = 0; ms < 4; ++ms)
                af[ms] = *reinterpret_cast<const bf16x8*>(&aL[wr*64 + ms*16 + l16][ks*32 + lhi*8]);
            #pragma unroll
            for (int ns = 0; ns < 4; ++ns)
                bg[ns] = *reinterpret_cast<const bf16x8*>(&bL[wc*64 + ns*16 + l16][ks*32 + lhi*8]);
            #pragma unroll
            for (int ms = 0; ms < 4; ++ms)
                #pragma unroll
                for (int ns = 0; ns < 4; ++ns)
                    acc[ms][ns] = mfma16(af[ms], bg[ns], acc[ms][ns]);
        }
    }

    #pragma unroll
    for (int ms = 0; ms < 4; ++ms)
    #pragma unroll
    for (int ns = 0; ns < 4; ++ns) {
        const int col = n0 + wc*64 + ns*16 + l16;
        const float bv = bo[col];
        #pragma unroll
        for (int i = 0; i < 4; ++i) {
            const int m = m0 + wr*64 + ms*16 + lhi*4 + i;
            dst[(size_t)m * 512 + col] = acc[ms][ns][i] + bv;
        }
    }
}

// ---- flash attention: QBLK=128 (32 q/wave), KV tile 32, dbuf gload_lds ----
// LDS = 32KB stg + 8KB pL = 40960B exactly -> 4 blocks/CU. nsp=4 -> 1024 blocks.
__global__ __launch_bounds__(256, 4) void attn_kernel(
    const bf16* __restrict__ Qr, const bf16* __restrict__ Qp,
    const bf16* __restrict__ Kr, const bf16* __restrict__ Kp,
    const bf16* __restrict__ Vtr, const bf16* __restrict__ Vtp,
    const int* __restrict__ mask, int lognsp,
    float* __restrict__ POR, float* __restrict__ POP, float* __restrict__ PLs)
{
    // K tensors: 32 key-rows x 8 chunks(16B) [d]; V tensors: 64 d-rows x 4 chunks [keys]
    __shared__ uint4 stg[2][4][256];   // 32KB
    __shared__ bf16 pL[4][1024];       // per-wave 16x64 folded P, 8KB

    const int F = blockIdx.x;
    const int qt = (F >> 3) & 15;
    const int g  = (F & 7) | ((F >> 7) << 3);     // (bh,z) groups pinned per XCD
    const int bh = g >> lognsp, z = g & ((1 << lognsp) - 1);
    const int Lkv = CS >> lognsp, kvbase = z * Lkv;
    const int nt = Lkv >> 5;
    const int b = bh >> 3;
    const size_t base = (size_t)bh * CS * CDK;

    const int tid = threadIdx.x, lane = tid & 63, w = tid >> 6;
    const int l16 = lane & 15, lhi = lane >> 4;
    const int q0 = qt * 128 + w * 32;

    // Q fragments: A-frag row = l16, k = ks*32 + lhi*8 + j
    bf16x8 qrf[2][2], qpf[2][2];
    #pragma unroll
    for (int ms = 0; ms < 2; ++ms)
        #pragma unroll
        for (int ks = 0; ks < 2; ++ks) {
            const size_t qoff = base + (size_t)(q0 + ms*16 + l16) * CDK + ks*32 + lhi*8;
            qrf[ms][ks] = *reinterpret_cast<const bf16x8*>(&Qr[qoff]);
            qpf[ms][ks] = *reinterpret_cast<const bf16x8*>(&Qp[qoff]);
        }

    f32x4 oR[2][4] = {}, oP[2][4] = {};
    float lpart[2][4] = {};

    // staging: wave w owns tensor w; pre-swizzled global source, linear LDS dest
    const char* gsrc = (w == 0) ? (const char*)Kr : (w == 1) ? (const char*)Kp
                     : (w == 2) ? (const char*)Vtr : (const char*)Vtp;
    size_t laneoff, iStride, tStride;
    if (w < 2) {   // K: row = i*8 + lane>>3, slot = lane&7 holds chunk slot^(row&7)
        laneoff = base*2 + (size_t)(kvbase + (lane >> 3)) * 128
                + (size_t)(((lane & 7) ^ (lane >> 3)) * 16);
        iStride = 8 * 128;  tStride = 32 * 128;
    } else {       // V: row = i*16 + lane>>2, slot = lane&3 holds chunk slot^((row>>1)&3)
        laneoff = base*2 + (size_t)(lane >> 2) * (CS*2) + (size_t)kvbase * 2
                + (size_t)((((lane & 3) ^ ((lane >> 3) & 3))) * 16);
        iStride = 16 * CS * 2;  tStride = 32 * 2;
    }
    const char* gp = gsrc + laneoff;

    auto stage = [&](int bi, int t) {
        const char* p = gp + (size_t)t * tStride;
        uint4* ldst = &stg[bi][w][0];
        #pragma unroll
        for (int i = 0; i < 4; ++i)
            gload16(p + i*iStride, ldst + i*64);
    };

    stage(0, 0);
    asm volatile("s_waitcnt vmcnt(0)" ::: "memory");
    __syncthreads();

    for (int t = 0; t < nt; ++t) {
        if (t + 1 < nt) stage((t + 1) & 1, t + 1);

        const int bi = t & 1;
        const int kvg = kvbase + t * 32;
        const unsigned int m32 =
            (unsigned int)__ballot(mask[b*CS + kvg + (lane & 31)] != 0);
        const uint4* kTr = &stg[bi][0][0];
        const uint4* kTp = &stg[bi][1][0];
        const uint4* vTr = &stg[bi][2][0];
        const uint4* vTp = &stg[bi][3][0];
        bf16* pB = &pL[w][0];

        #pragma unroll
        for (int kb = 0; kb < 2; ++kb) {
            const int krow = kb*16 + l16;
            bf16x8 kr8[2], kp8[2], kn8[2];
            #pragma unroll
            for (int ks = 0; ks < 2; ++ks) {
                const int ci = krow*8 + ((ks*4 + lhi) ^ (krow & 7));
                kr8[ks] = __builtin_bit_cast(bf16x8, kTr[ci]);
                kp8[ks] = __builtin_bit_cast(bf16x8, kTp[ci]);
                uint4 tn = __builtin_bit_cast(uint4, kp8[ks]);
                tn.x ^= 0x80008000u; tn.y ^= 0x80008000u;
                tn.z ^= 0x80008000u; tn.w ^= 0x80008000u;
                kn8[ks] = __builtin_bit_cast(bf16x8, tn);   // -kp exact
            }
            const unsigned int keep16 = m32 >> (kb*16 + l16);
            #pragma unroll
            for (int ms = 0; ms < 2; ++ms) {
                f32x4 aR = {}, aP = {};
                #pragma unroll
                for (int ks = 0; ks < 2; ++ks) {
                    aR = mfma16(qrf[ms][ks], kr8[ks], aR);
                    aR = mfma16(qpf[ms][ks], kn8[ks], aR);
                    aP = mfma16(qrf[ms][ks], kp8[ks], aP);
                    aP = mfma16(qpf[ms][ks], kr8[ks], aP);
                }
                #pragma unroll
                for (int i = 0; i < 4; ++i) {
                    const float sr = aR[i], sp = aP[i];
                    const float mag = __builtin_amdgcn_sqrtf(fmaf(sr, sr, sp*sp));
                    float p = __builtin_amdgcn_exp2f(fmaf(mag, 0.18033688f, -5.77078016f));
                    p = (keep16 & 1u) ? p : 0.0f;
                    lpart[ms][i] += p;
                    // folded P write: r=q&15, col=(q>>4)*32 + key
                    const int r = lhi*4 + i;
                    const int chunk = ms*4 + kb*2 + (l16 >> 3);
                    const int byteoff = r*128 + ((chunk ^ (r & 7)) << 4) + (l16 & 7)*2;
                    *reinterpret_cast<bf16*>(reinterpret_cast<char*>(pB) + byteoff) = (bf16)p;
                }
            }
        }
        asm volatile("s_waitcnt lgkmcnt(0)" ::: "memory");
        __builtin_amdgcn_sched_barrier(0);

        // PV: 32-key contraction, 1 A-chunk per ms
        const uint4* pW = reinterpret_cast<const uint4*>(pB);
        bf16x8 pf[2];
        #pragma unroll
        for (int ms = 0; ms < 2; ++ms)
            pf[ms] = __builtin_bit_cast(bf16x8, pW[l16*8 + ((ms*4 + lhi) ^ (l16 & 7))]);
        #pragma unroll
        for (int d = 0; d < 4; ++d) {
            const int vrow = d*16 + l16;
            const int ci = vrow*4 + (lhi ^ ((vrow >> 1) & 3));
            const bf16x8 v8r = __builtin_bit_cast(bf16x8, vTr[ci]);
            const bf16x8 v8p = __builtin_bit_cast(bf16x8, vTp[ci]);
            #pragma unroll
            for (int ms = 0; ms < 2; ++ms) {
                oR[ms][d] = mfma16(pf[ms], v8r, oR[ms][d]);
                oP[ms][d] = mfma16(pf[ms], v8p, oP[ms][d]);
            }
        }

        if (t + 1 < nt) __syncthreads();
    }

    // epilogue: reduce l across the 16-lane row group, store partials [z][row][64]
    #pragma unroll
    for (int ms = 0; ms < 2; ++ms)
        #pragma unroll
        for (int i = 0; i < 4; ++i) {
            float v = lpart[ms][i];
            v += __shfl_xor(v, 1); v += __shfl_xor(v, 2);
            v += __shfl_xor(v, 4); v += __shfl_xor(v, 8);
            lpart[ms][i] = v;
        }
    const int r0 = bh * CS + q0;
    if (l16 == 0) {
        #pragma unroll
        for (int ms = 0; ms < 2; ++ms)
            #pragma unroll
            for (int i = 0; i < 4; ++i)
                PLs[(size_t)z * NROWS + r0 + ms*16 + lhi*4 + i] = lpart[ms][i];
    }
    const size_t zo = (size_t)z * NROWS * 64;
    #pragma unroll
    for (int ms = 0; ms < 2; ++ms)
        #pragma unroll
        for (int d = 0; d < 4; ++d) {
            const int col = d*16 + l16;
            #pragma unroll
            for (int i = 0; i < 4; ++i) {
                const size_t off = zo + (size_t)(r0 + ms*16 + lhi*4 + i) * 64 + col;
                POR[off] = oR[ms][d][i];
                POP[off] = oP[ms][d][i];
            }
        }
}

// ---- combine KV-split partials, normalize, write [B,S,D] bf16 (x4 vectorized) ----
__global__ __launch_bounds__(256) void merge_kernel(
    const float* __restrict__ POR, const float* __restrict__ POP,
    const float* __restrict__ PLs, int nsp,
    bf16* __restrict__ Xr, bf16* __restrict__ Xp)
{
    const int idx = blockIdx.x * 256 + threadIdx.x;   // 0 .. NROWS*16-1
    const int r = idx >> 4, c0 = (idx & 15) * 4;
    float l = 0.f;
    f32x4 orv = {}, opv = {};
    for (int zz = 0; zz < nsp; ++zz) {
        l += PLs[(size_t)zz * NROWS + r];
        const size_t o = (size_t)zz * NROWS * 64 + (size_t)r * 64 + c0;
        orv += *reinterpret_cast<const f32x4*>(&POR[o]);
        opv += *reinterpret_cast<const f32x4*>(&POP[o]);
    }
    const float inv = 1.f / l;
    const int bh = r >> 11, q = r & 2047;
    const int b = bh >> 3, h = bh & 7;
    const size_t off = ((size_t)(b*CS + q)) * CD + h*CDK + c0;
    bf16 vr[4], vp[4];
    #pragma unroll
    for (int j = 0; j < 4; ++j) { vr[j] = (bf16)(orv[j]*inv); vp[j] = (bf16)(opv[j]*inv); }
    *reinterpret_cast<uint2*>(&Xr[off]) = *reinterpret_cast<const uint2*>(vr);
    *reinterpret_cast<uint2*>(&Xp[off]) = *reinterpret_cast<const uint2*>(vp);
}

extern "C" void kernel_launch(void* const* d_in, const int* in_sizes, int n_in,
                              void* d_out, int out_size, void* d_ws, size_t ws_size,
                              hipStream_t stream) {
    const float* q_r = (const float*)d_in[0];
    const float* k_r = (const float*)d_in[1];
    const float* v_r = (const float*)d_in[2];
    const float* q_p = (const float*)d_in[3];
    const float* k_p = (const float*)d_in[4];
    const float* v_p = (const float*)d_in[5];
    const int*  mask = (const int*)d_in[6];
    const float* Wq = (const float*)d_in[7];  const float* bq = (const float*)d_in[8];
    const float* Wk = (const float*)d_in[9];  const float* bk = (const float*)d_in[10];
    const float* Wv = (const float*)d_in[11]; const float* bv = (const float*)d_in[12];
    const float* Wo = (const float*)d_in[13]; const float* bo = (const float*)d_in[14];
    float* out = (float*)d_out;

    bf16* ws = (bf16*)d_ws;
    bf16 *Qr = ws,        *Qp = Qr + NT;
    bf16 *Kr = Qp + NT,   *Kp = Kr + NT;
    bf16 *Vtr = Kp + NT,  *Vtp = Vtr + NT;
    bf16 *Xr = Vtp + NT,  *Xp = Xr + NT;     // 8 * NT * 2B = 33.55 MB
    float* POR = (float*)(ws + 8 * NT);

    const size_t fixed = 8 * NT * sizeof(bf16);
    const size_t per_split = (size_t)NROWS * 64 * 4 * 2 + (size_t)NROWS * 4;
    int nsp, lognsp;
    if (ws_size >= fixed + 4 * per_split)      { nsp = 4; lognsp = 2; }
    else if (ws_size >= fixed + 2 * per_split) { nsp = 2; lognsp = 1; }
    else                                       { nsp = 1; lognsp = 0; }
    float* POP = POR + (size_t)nsp * NROWS * 64;
    float* PLs = POP + (size_t)nsp * NROWS * 64;

    dim3 blk(256);

    PPtrs P;
    P.A[0]=q_r; P.A[1]=q_p; P.A[2]=k_r; P.A[3]=k_p; P.A[4]=v_r; P.A[5]=v_p;
    P.W[0]=Wq;  P.W[1]=Wq;  P.W[2]=Wk;  P.W[3]=Wk;  P.W[4]=Wv;  P.W[5]=Wv;
    P.bias[0]=bq; P.bias[1]=bq; P.bias[2]=bk; P.bias[3]=bk; P.bias[4]=bv; P.bias[5]=bv;
    P.dst[0]=Qr; P.dst[1]=Qp; P.dst[2]=Kr; P.dst[3]=Kp; P.dst[4]=Vtr; P.dst[5]=Vtp;
    P.mode[0]=0; P.mode[1]=0; P.mode[2]=0; P.mode[3]=0; P.mode[4]=1; P.mode[5]=1;

    proj_kernel<<<dim3(32, 4, 6), blk, 0, stream>>>(P);

    attn_kernel<<<dim3(256 * nsp), blk, 0, stream>>>(Qr, Qp, Kr, Kp, Vtr, Vtp,
                                                     mask, lognsp, POR, POP, PLs);

    merge_kernel<<<dim3(NROWS * 16 / 256), blk, 0, stream>>>(POR, POP, PLs, nsp, Xr, Xp);

    oproj_kernel<<<dim3(32, 4, 2), blk, 0, stream>>>(Xr, Xp, Wo, bo, out);
}

// Round 6
// 162.103 us; speedup vs baseline: 2.4848x; 2.4848x over previous
//
#include <hip/hip_runtime.h>

typedef __bf16 bf16;
typedef __bf16 bf16x8 __attribute__((ext_vector_type(8)));
typedef float  f32x4  __attribute__((ext_vector_type(4)));

static constexpr int CB = 2;     // batch
static constexpr int CS = 2048;  // seq
static constexpr int CD = 512;   // model dim
static constexpr int CH = 8;     // heads
static constexpr int CDK = 64;   // head dim
static constexpr int NROWS = CB * CH * CS;         // 32768 attention rows
static constexpr size_t NT = (size_t)CB * CS * CD; // 2,097,152 elements per tensor

__device__ __forceinline__ f32x4 mfma16(bf16x8 a, bf16x8 b, f32x4 c) {
    return __builtin_amdgcn_mfma_f32_16x16x32_bf16(a, b, c, 0, 0, 0);
}

__device__ __forceinline__ bf16x8 cvt8(const float* __restrict__ p) {
    float4 x0 = *reinterpret_cast<const float4*>(p);
    float4 x1 = *reinterpret_cast<const float4*>(p + 4);
    bf16x8 r;
    r[0] = (bf16)x0.x; r[1] = (bf16)x0.y; r[2] = (bf16)x0.z; r[3] = (bf16)x0.w;
    r[4] = (bf16)x1.x; r[5] = (bf16)x1.y; r[6] = (bf16)x1.z; r[7] = (bf16)x1.w;
    return r;
}

__device__ __forceinline__ void gload16(const void* g, void* l) {
    __builtin_amdgcn_global_load_lds(
        (const __attribute__((address_space(1))) void*)g,
        (__attribute__((address_space(3))) void*)l, 16, 0, 0);
}

struct PPtrs {
    const float* A[6];
    const float* W[6];
    const float* bias[6];
    bf16* dst[6];
    int mode[6];   // 0: [B,H,S,DK]   1: [B,H,DK,S] (transposed V)
};

// ---- merged projection GEMM, 128x128 tile: C[m,n] = sum_k A[m,k]*W[n,k] + bias[n] ----
__global__ __launch_bounds__(256) void proj_kernel(PPtrs P) {
    __shared__ bf16 aL[128][72];
    __shared__ bf16 bL[128][72];
    const int z = blockIdx.z;
    const float* __restrict__ A    = P.A[z];
    const float* __restrict__ Bt   = P.W[z];
    const float* __restrict__ bias = P.bias[z];
    bf16* __restrict__ dst = P.dst[z];
    const int mode = P.mode[z];

    const int m0 = blockIdx.x * 128, n0 = blockIdx.y * 128;
    const int tid = threadIdx.x;
    const int lane = tid & 63, w = tid >> 6;
    const int wr = w >> 1, wc = w & 1;
    const int l16 = lane & 15, lhi = lane >> 4;
    const int srow = tid >> 1, sk = (tid & 1) * 32;

    f32x4 acc[4][4] = {};

    for (int k0 = 0; k0 < 512; k0 += 64) {
        __syncthreads();
        #pragma unroll
        for (int c = 0; c < 4; ++c) {
            *reinterpret_cast<bf16x8*>(&aL[srow][sk + c*8]) =
                cvt8(A + (size_t)(m0 + srow) * 512 + k0 + sk + c*8);
            *reinterpret_cast<bf16x8*>(&bL[srow][sk + c*8]) =
                cvt8(Bt + (size_t)(n0 + srow) * 512 + k0 + sk + c*8);
        }
        __syncthreads();

        #pragma unroll
        for (int ks = 0; ks < 2; ++ks) {
            bf16x8 af[4], bg[4];
            #pragma unroll
            for (int ms = 0; ms < 4; ++ms)
                af[ms] = *reinterpret_cast<const bf16x8*>(&aL[wr*64 + ms*16 + l16][ks*32 + lhi*8]);
            #pragma unroll
            for (int ns = 0; ns < 4; ++ns)
                bg[ns] = *reinterpret_cast<const bf16x8*>(&bL[wc*64 + ns*16 + l16][ks*32 + lhi*8]);
            #pragma unroll
            for (int ms = 0; ms < 4; ++ms)
                #pragma unroll
                for (int ns = 0; ns < 4; ++ns)
                    acc[ms][ns] = mfma16(af[ms], bg[ns], acc[ms][ns]);
        }
    }

    #pragma unroll
    for (int ms = 0; ms < 4; ++ms)
    #pragma unroll
    for (int ns = 0; ns < 4; ++ns) {
        const int col = n0 + wc*64 + ns*16 + l16;
        const float bv = bias[col];
        const int hh = col >> 6, dk = col & 63;
        #pragma unroll
        for (int i = 0; i < 4; ++i) {
            const int m = m0 + wr*64 + ms*16 + lhi*4 + i;
            const float v = acc[ms][ns][i] + bv;
            const int b = m >> 11, s = m & 2047;
            if (mode == 0)
                dst[(((size_t)(b*CH + hh)) * CS + s) * CDK + dk] = (bf16)v;
            else
                dst[(((size_t)(b*CH + hh)) * CDK + dk) * CS + s] = (bf16)v;
        }
    }
}

// ---- output GEMM, 128x128 tile ----
__global__ __launch_bounds__(256) void oproj_kernel(
    const bf16* __restrict__ Xr, const bf16* __restrict__ Xp,
    const float* __restrict__ Wo, const float* __restrict__ bo,
    float* __restrict__ out)
{
    __shared__ bf16 aL[128][72];
    __shared__ bf16 bL[128][72];
    const bf16* __restrict__ A = blockIdx.z ? Xp : Xr;
    float* __restrict__ dst = out + (size_t)blockIdx.z * NT;

    const int m0 = blockIdx.x * 128, n0 = blockIdx.y * 128;
    const int tid = threadIdx.x;
    const int lane = tid & 63, w = tid >> 6;
    const int wr = w >> 1, wc = w & 1;
    const int l16 = lane & 15, lhi = lane >> 4;
    const int srow = tid >> 1, sk = (tid & 1) * 32;

    f32x4 acc[4][4] = {};

    for (int k0 = 0; k0 < 512; k0 += 64) {
        __syncthreads();
        #pragma unroll
        for (int c = 0; c < 4; ++c) {
            *reinterpret_cast<bf16x8*>(&aL[srow][sk + c*8]) =
                *reinterpret_cast<const bf16x8*>(A + (size_t)(m0 + srow) * 512 + k0 + sk + c*8);
            *reinterpret_cast<bf16x8*>(&bL[srow][sk + c*8]) =
                cvt8(Wo + (size_t)(n0 + srow) * 512 + k0 + sk + c*8);
        }
        __syncthreads();

        #pragma unroll
        for (int ks = 0; ks < 2; ++ks) {
            bf16x8 af[4], bg[4];
            #pragma unroll
            for (int ms = 0; ms < 4; ++ms)
                af[ms] = *reinterpret_cast<const bf16x8*>(&aL[wr*64 + ms*16 + l16][ks*32 + lhi*8]);
            #pragma unroll
            for (int ns = 0; ns < 4; ++ns)
                bg[ns] = *reinterpret_cast<const bf16x8*>(&bL[wc*64 + ns*16 + l16][ks*32 + lhi*8]);
            #pragma unroll
            for (int ms = 0; ms < 4; ++ms)
                #pragma unroll
                for (int ns = 0; ns < 4; ++ns)
                    acc[ms][ns] = mfma16(af[ms], bg[ns], acc[ms][ns]);
        }
    }

    #pragma unroll
    for (int ms = 0; ms < 4; ++ms)
    #pragma unroll
    for (int ns = 0; ns < 4; ++ns) {
        const int col = n0 + wc*64 + ns*16 + l16;
        const float bv = bo[col];
        #pragma unroll
        for (int i = 0; i < 4; ++i) {
            const int m = m0 + wr*64 + ms*16 + lhi*4 + i;
            dst[(size_t)m * 512 + col] = acc[ms][ns][i] + bv;
        }
    }
}

// ---- flash attention: QBLK=128 (32 q/wave, 2 subtiles), KV tile 64, dbuf gload_lds ----
// grid 16qt*16bh*nsp 1D XCD-swizzled. LDS = 64KB K/V dbuf + 16KB pL = 80KB (2 blk/CU).
// Mask handled via prologue bitmap (2 VGPR) -> NO per-iter vmem in the loop body,
// so the t+1 prefetch drains only at the end-of-iter barrier (latency hidden).
__global__ __launch_bounds__(256) void attn_kernel(
    const bf16* __restrict__ Qr, const bf16* __restrict__ Qp,
    const bf16* __restrict__ Kr, const bf16* __restrict__ Kp,
    const bf16* __restrict__ Vtr, const bf16* __restrict__ Vtp,
    const int* __restrict__ mask, int lognsp,
    float* __restrict__ POR, float* __restrict__ POP, float* __restrict__ PLs)
{
    __shared__ uint4 stg[2][4][512];   // [buf][tensor Kr,Kp,Vtr,Vtp][row*8+slot] 64KB
    __shared__ bf16 pL[4][32][64];     // per-wave P, XOR-swizzled, 16KB

    const int F = blockIdx.x;
    const int qt = (F >> 3) & 15;
    const int g  = (F & 7) | ((F >> 7) << 3);     // (bh,z) groups pinned per XCD
    const int bh = g >> lognsp, z = g & ((1 << lognsp) - 1);
    const int Lkv = CS >> lognsp, kvbase = z * Lkv;
    const int nt = Lkv >> 6;
    const int b = bh >> 3;
    const size_t base = (size_t)bh * CS * CDK;

    const int tid = threadIdx.x, lane = tid & 63, w = tid >> 6;
    const int l16 = lane & 15, lhi = lane >> 4;
    const int q0 = qt * 128 + w * 32;

    // staging: wave w owns tensor w; per-lane pre-swizzled global source,
    // linear LDS dest (slot l%8 holds global chunk (l%8)^(l/8))
    const int srowL = lane >> 3, slotL = lane & 7;
    const int chunkL = slotL ^ srowL;
    const char* gsrc;
    size_t laneoff, iStride, tStride;
    if (w == 0)      gsrc = (const char*)Kr;
    else if (w == 1) gsrc = (const char*)Kp;
    else if (w == 2) gsrc = (const char*)Vtr;
    else             gsrc = (const char*)Vtp;
    if (w < 2) {
        laneoff = base*2 + (size_t)(kvbase + srowL) * 128 + chunkL*16;
        iStride = 1024;  tStride = 8192;
    } else {
        laneoff = base*2 + (size_t)srowL * (CS*2) + (size_t)kvbase*2 + chunkL*16;
        iStride = 8 * CS * 2;  tStride = 128;
    }
    const char* gp = gsrc + laneoff;

    auto stage = [&](int bi, int t) {
        const char* p = gp + (size_t)t * tStride;
        uint4* ldst = &stg[bi][w][0];
        #pragma unroll
        for (int i = 0; i < 8; ++i)
            gload16(p + i*iStride, ldst + i*64);
    };

    stage(0, 0);   // issue first tile ASAP; prologue work below overlaps it

    // Q fragments for 2 subtiles: A-frag row = l16, k = ks*32 + lhi*8 + j
    bf16x8 qrf[2][2], qpf[2][2], qnf[2][2];
    #pragma unroll
    for (int ms = 0; ms < 2; ++ms)
        #pragma unroll
        for (int ks = 0; ks < 2; ++ks) {
            const size_t qoff = base + (size_t)(q0 + ms*16 + l16) * CDK + ks*32 + lhi*8;
            qrf[ms][ks] = *reinterpret_cast<const bf16x8*>(&Qr[qoff]);
            qpf[ms][ks] = *reinterpret_cast<const bf16x8*>(&Qp[qoff]);
            uint4 t = __builtin_bit_cast(uint4, qpf[ms][ks]);
            t.x ^= 0x80008000u; t.y ^= 0x80008000u; t.z ^= 0x80008000u; t.w ^= 0x80008000u;
            qnf[ms][ks] = __builtin_bit_cast(bf16x8, t);   // -qp exact
        }

    // mask bitmap prologue: per-lane 4 bits per KV tile (keys kb*16 + l16).
    // nt <= 32 (nsp>=1) -> two 64-bit accumulators.
    unsigned long long keep4[2] = {0ull, 0ull};
    for (int t = 0; t < nt; ++t) {
        const unsigned long long m64 =
            __ballot(mask[b*CS + kvbase + t*64 + lane] != 0);
        const unsigned long long bits = m64 >> l16;
        const unsigned long long nib =
            (bits & 1ull) | ((bits >> 15) & 2ull) | ((bits >> 30) & 4ull) | ((bits >> 45) & 8ull);
        keep4[t >> 4] |= nib << ((t & 15) * 4);
    }

    f32x4 oR[2][4] = {}, oP[2][4] = {};
    float lpart[2][4] = {};

    // pL swizzle: injective on stride-1 (reads) and stride-4 (writes) row groups
    auto fswz = [](int r) { return (r & 7) ^ (((r >> 3) & 1) << 1); };

    asm volatile("s_waitcnt vmcnt(0)" ::: "memory");
    __syncthreads();

    for (int t = 0; t < nt; ++t) {
        if (t + 1 < nt) stage((t + 1) & 1, t + 1);

        const int bi = t & 1;
        const unsigned int k4 = (unsigned int)(keep4[t >> 4] >> ((t & 15) * 4)) & 0xFu;
        const uint4* kTr = &stg[bi][0][0];
        const uint4* kTp = &stg[bi][1][0];
        const uint4* vTr = &stg[bi][2][0];
        const uint4* vTp = &stg[bi][3][0];

        float sc[2][4][4];
        #pragma unroll
        for (int kb = 0; kb < 4; ++kb) {
            const int krow = kb*16 + l16;
            bf16x8 kr8[2], kp8[2];
            #pragma unroll
            for (int ks = 0; ks < 2; ++ks) {
                const int ci = krow*8 + ((ks*4 + lhi) ^ (krow & 7));
                kr8[ks] = __builtin_bit_cast(bf16x8, kTr[ci]);
                kp8[ks] = __builtin_bit_cast(bf16x8, kTp[ci]);
            }
            const unsigned int keep = (k4 >> kb) & 1u;
            #pragma unroll
            for (int ms = 0; ms < 2; ++ms) {
                f32x4 aR = {}, aP = {};
                __builtin_amdgcn_s_setprio(1);
                #pragma unroll
                for (int ks = 0; ks < 2; ++ks) {
                    aR = mfma16(qrf[ms][ks], kr8[ks], aR);
                    aR = mfma16(qnf[ms][ks], kp8[ks], aR);
                    aP = mfma16(qrf[ms][ks], kp8[ks], aP);
                    aP = mfma16(qpf[ms][ks], kr8[ks], aP);
                }
                __builtin_amdgcn_s_setprio(0);
                #pragma unroll
                for (int i = 0; i < 4; ++i) {
                    const float sr = aR[i], sp = aP[i];
                    const float mag = __builtin_amdgcn_sqrtf(fmaf(sr, sr, sp*sp));
                    float p = __builtin_amdgcn_exp2f(fmaf(mag, 0.18033688f, -5.77078016f));
                    p = keep ? p : 0.0f;
                    sc[ms][kb][i] = p;
                    lpart[ms][i] += p;
                }
            }
        }

        // write P (both subtiles) to per-wave swizzled pL
        bf16* pB = &pL[w][0][0];
        #pragma unroll
        for (int ms = 0; ms < 2; ++ms)
            #pragma unroll
            for (int i = 0; i < 4; ++i) {
                const int row = ms*16 + lhi*4 + i;
                const int sw = fswz(row) << 3;
                #pragma unroll
                for (int kb = 0; kb < 4; ++kb)
                    pB[row*64 + ((kb*16 + l16) ^ sw)] = (bf16)sc[ms][kb][i];
            }
        asm volatile("s_waitcnt lgkmcnt(0)" ::: "memory");
        __builtin_amdgcn_sched_barrier(0);

        // PV: V-frags shared across both subtiles
        const uint4* pW = reinterpret_cast<const uint4*>(&pL[w][0][0]);
        #pragma unroll
        for (int ks = 0; ks < 2; ++ks) {
            bf16x8 pf[2];
            #pragma unroll
            for (int ms = 0; ms < 2; ++ms) {
                const int prow = ms*16 + l16;
                pf[ms] = __builtin_bit_cast(bf16x8, pW[prow*8 + ((ks*4 + lhi) ^ fswz(prow))]);
            }
            __builtin_amdgcn_s_setprio(1);
            #pragma unroll
            for (int d = 0; d < 4; ++d) {
                const int vrow = d*16 + l16;
                const int ci = vrow*8 + ((ks*4 + lhi) ^ (vrow & 7));
                const bf16x8 v8r = __builtin_bit_cast(bf16x8, vTr[ci]);
                const bf16x8 v8p = __builtin_bit_cast(bf16x8, vTp[ci]);
                #pragma unroll
                for (int ms = 0; ms < 2; ++ms) {
                    oR[ms][d] = mfma16(pf[ms], v8r, oR[ms][d]);
                    oP[ms][d] = mfma16(pf[ms], v8p, oP[ms][d]);
                }
            }
            __builtin_amdgcn_s_setprio(0);
        }

        if (t + 1 < nt) __syncthreads();
    }

    // epilogue: reduce l across the 16-lane row group, store partials [z][row][64]
    #pragma unroll
    for (int ms = 0; ms < 2; ++ms)
        #pragma unroll
        for (int i = 0; i < 4; ++i) {
            float v = lpart[ms][i];
            v += __shfl_xor(v, 1); v += __shfl_xor(v, 2);
            v += __shfl_xor(v, 4); v += __shfl_xor(v, 8);
            lpart[ms][i] = v;
        }
    const int r0 = bh * CS + q0;
    if (l16 == 0) {
        #pragma unroll
        for (int ms = 0; ms < 2; ++ms)
            #pragma unroll
            for (int i = 0; i < 4; ++i)
                PLs[(size_t)z * NROWS + r0 + ms*16 + lhi*4 + i] = lpart[ms][i];
    }
    const size_t zo = (size_t)z * NROWS * 64;
    #pragma unroll
    for (int ms = 0; ms < 2; ++ms)
        #pragma unroll
        for (int d = 0; d < 4; ++d) {
            const int col = d*16 + l16;
            #pragma unroll
            for (int i = 0; i < 4; ++i) {
                const size_t off = zo + (size_t)(r0 + ms*16 + lhi*4 + i) * 64 + col;
                POR[off] = oR[ms][d][i];
                POP[off] = oP[ms][d][i];
            }
        }
}

// ---- combine KV-split partials, normalize, write [B,S,D] bf16 (x4 vectorized) ----
__global__ __launch_bounds__(256) void merge_kernel(
    const float* __restrict__ POR, const float* __restrict__ POP,
    const float* __restrict__ PLs, int nsp,
    bf16* __restrict__ Xr, bf16* __restrict__ Xp)
{
    const int idx = blockIdx.x * 256 + threadIdx.x;   // 0 .. NROWS*16-1
    const int r = idx >> 4, c0 = (idx & 15) * 4;
    float l = 0.f;
    f32x4 orv = {}, opv = {};
    for (int zz = 0; zz < nsp; ++zz) {
        l += PLs[(size_t)zz * NROWS + r];
        const size_t o = (size_t)zz * NROWS * 64 + (size_t)r * 64 + c0;
        orv += *reinterpret_cast<const f32x4*>(&POR[o]);
        opv += *reinterpret_cast<const f32x4*>(&POP[o]);
    }
    const float inv = 1.f / l;
    const int bh = r >> 11, q = r & 2047;
    const int b = bh >> 3, h = bh & 7;
    const size_t off = ((size_t)(b*CS + q)) * CD + h*CDK + c0;
    bf16 vr[4], vp[4];
    #pragma unroll
    for (int j = 0; j < 4; ++j) { vr[j] = (bf16)(orv[j]*inv); vp[j] = (bf16)(opv[j]*inv); }
    *reinterpret_cast<uint2*>(&Xr[off]) = *reinterpret_cast<const uint2*>(vr);
    *reinterpret_cast<uint2*>(&Xp[off]) = *reinterpret_cast<const uint2*>(vp);
}

extern "C" void kernel_launch(void* const* d_in, const int* in_sizes, int n_in,
                              void* d_out, int out_size, void* d_ws, size_t ws_size,
                              hipStream_t stream) {
    const float* q_r = (const float*)d_in[0];
    const float* k_r = (const float*)d_in[1];
    const float* v_r = (const float*)d_in[2];
    const float* q_p = (const float*)d_in[3];
    const float* k_p = (const float*)d_in[4];
    const float* v_p = (const float*)d_in[5];
    const int*  mask = (const int*)d_in[6];
    const float* Wq = (const float*)d_in[7];  const float* bq = (const float*)d_in[8];
    const float* Wk = (const float*)d_in[9];  const float* bk = (const float*)d_in[10];
    const float* Wv = (const float*)d_in[11]; const float* bv = (const float*)d_in[12];
    const float* Wo = (const float*)d_in[13]; const float* bo = (const float*)d_in[14];
    float* out = (float*)d_out;

    bf16* ws = (bf16*)d_ws;
    bf16 *Qr = ws,        *Qp = Qr + NT;
    bf16 *Kr = Qp + NT,   *Kp = Kr + NT;
    bf16 *Vtr = Kp + NT,  *Vtp = Vtr + NT;
    bf16 *Xr = Vtp + NT,  *Xp = Xr + NT;     // 8 * NT * 2B = 33.55 MB
    float* POR = (float*)(ws + 8 * NT);

    const size_t fixed = 8 * NT * sizeof(bf16);
    const size_t per_split = (size_t)NROWS * 64 * 4 * 2 + (size_t)NROWS * 4;
    int nsp, lognsp;
    if (ws_size >= fixed + 2 * per_split) { nsp = 2; lognsp = 1; }
    else                                  { nsp = 1; lognsp = 0; }
    float* POP = POR + (size_t)nsp * NROWS * 64;
    float* PLs = POP + (size_t)nsp * NROWS * 64;

    dim3 blk(256);

    PPtrs P;
    P.A[0]=q_r; P.A[1]=q_p; P.A[2]=k_r; P.A[3]=k_p; P.A[4]=v_r; P.A[5]=v_p;
    P.W[0]=Wq;  P.W[1]=Wq;  P.W[2]=Wk;  P.W[3]=Wk;  P.W[4]=Wv;  P.W[5]=Wv;
    P.bias[0]=bq; P.bias[1]=bq; P.bias[2]=bk; P.bias[3]=bk; P.bias[4]=bv; P.bias[5]=bv;
    P.dst[0]=Qr; P.dst[1]=Qp; P.dst[2]=Kr; P.dst[3]=Kp; P.dst[4]=Vtr; P.dst[5]=Vtp;
    P.mode[0]=0; P.mode[1]=0; P.mode[2]=0; P.mode[3]=0; P.mode[4]=1; P.mode[5]=1;

    proj_kernel<<<dim3(32, 4, 6), blk, 0, stream>>>(P);

    attn_kernel<<<dim3(256 * nsp), blk, 0, stream>>>(Qr, Qp, Kr, Kp, Vtr, Vtp,
                                                     mask, lognsp, POR, POP, PLs);

    merge_kernel<<<dim3(NROWS * 16 / 256), blk, 0, stream>>>(POR, POP, PLs, nsp, Xr, Xp);

    oproj_kernel<<<dim3(32, 4, 2), blk, 0, stream>>>(Xr, Xp, Wo, bo, out);
}

// Round 7
// 128.133 us; speedup vs baseline: 3.1435x; 1.2651x over previous
//
#include <hip/hip_runtime.h>

typedef __bf16 bf16;
typedef __bf16 bf16x8 __attribute__((ext_vector_type(8)));
typedef float  f32x4  __attribute__((ext_vector_type(4)));

static constexpr int CB = 2;     // batch
static constexpr int CS = 2048;  // seq
static constexpr int CD = 512;   // model dim
static constexpr int CH = 8;     // heads
static constexpr int CDK = 64;   // head dim
static constexpr int NROWS = CB * CH * CS;         // 32768 attention rows
static constexpr size_t NT = (size_t)CB * CS * CD; // 2,097,152 elements per tensor
static constexpr size_t WN = (size_t)CD * CD;      // 262,144 weight elements

__device__ __forceinline__ f32x4 mfma16(bf16x8 a, bf16x8 b, f32x4 c) {
    return __builtin_amdgcn_mfma_f32_16x16x32_bf16(a, b, c, 0, 0, 0);
}

__device__ __forceinline__ bf16x8 cvt8(const float* __restrict__ p) {
    float4 x0 = *reinterpret_cast<const float4*>(p);
    float4 x1 = *reinterpret_cast<const float4*>(p + 4);
    bf16x8 r;
    r[0] = (bf16)x0.x; r[1] = (bf16)x0.y; r[2] = (bf16)x0.z; r[3] = (bf16)x0.w;
    r[4] = (bf16)x1.x; r[5] = (bf16)x1.y; r[6] = (bf16)x1.z; r[7] = (bf16)x1.w;
    return r;
}

__device__ __forceinline__ void gload16(const void* g, void* l) {
    __builtin_amdgcn_global_load_lds(
        (const __attribute__((address_space(1))) void*)g,
        (__attribute__((address_space(3))) void*)l, 16, 0, 0);
}

// ---- f32 -> bf16 conversion pass (inputs + weights) ----
struct CvtP {
    const float* src[10];
    bf16* dst[10];
    int n8[10];       // elements/8
};
__global__ __launch_bounds__(256) void cvt_kernel(CvtP C) {
    const int t = blockIdx.y;
    const int i = blockIdx.x * 256 + threadIdx.x;
    if (i < C.n8[t])
        *reinterpret_cast<bf16x8*>(C.dst[t] + (size_t)i * 8) =
            cvt8(C.src[t] + (size_t)i * 8);
}

// ---- merged projection GEMM (bf16 in), 64x64 tile, gload_lds dbuf ----
// C[m,n] = sum_k A[m,k]*W[n,k] + bias[n].  M=4096, N=512, K=512. grid (64,8,6).
struct PB {
    const bf16* A[6];
    const bf16* W[6];
    const float* bias[6];
    bf16* dst[6];
    int mode[6];   // 0: [B,H,S,DK]   1: [B,H,DK,S]
};
__global__ __launch_bounds__(256) void projb_kernel(PB P) {
    __shared__ uint4 tile[2][2][512];   // [buf][A/B][row*8+slot] 32KB, XOR-swizzled

    const int z = blockIdx.z;
    const bf16* __restrict__ A = P.A[z];
    const bf16* __restrict__ W = P.W[z];
    const float* __restrict__ bias = P.bias[z];
    bf16* __restrict__ dst = P.dst[z];
    const int mode = P.mode[z];

    const int m0 = blockIdx.x * 64, n0 = blockIdx.y * 64;
    const int tid = threadIdx.x;
    const int lane = tid & 63, w = tid >> 6;
    const int wm = w >> 1, wn = w & 1;
    const int l16 = lane & 15, lhi = lane >> 4;

    // staging: wave w -> tensor (w>>1), row half (w&1)
    const int tensor = w >> 1, half = w & 1;
    const int rlo = lane >> 3, slotL = lane & 7;     // row&7 == rlo
    const bf16* gbase = tensor ? W : A;
    const int t0 = tensor ? n0 : m0;
    const char* gp = (const char*)gbase
                   + (size_t)(t0 + half*32 + rlo) * (CD * 2)
                   + (size_t)((slotL ^ rlo) * 16);

    auto stage = [&](int buf, int kk) {
        const char* p = gp + (size_t)kk * 128;       // 64 bf16 per k-step
        uint4* ld = &tile[buf][tensor][half * 256];
        #pragma unroll
        for (int i = 0; i < 4; ++i)
            gload16(p + (size_t)i * 8 * (CD * 2), ld + i * 64);
    };

    f32x4 acc[2][2] = {};

    stage(0, 0);
    asm volatile("s_waitcnt vmcnt(0)" ::: "memory");
    __syncthreads();

    for (int kk = 0; kk < 8; ++kk) {
        if (kk + 1 < 8) stage((kk + 1) & 1, kk + 1);

        const uint4* aT = &tile[kk & 1][0][0];
        const uint4* bT = &tile[kk & 1][1][0];
        #pragma unroll
        for (int ks = 0; ks < 2; ++ks) {
            const int c = ks*4 + lhi;
            const int ra0 = wm*32 + l16, ra1 = ra0 + 16;
            const int rb0 = wn*32 + l16, rb1 = rb0 + 16;
            bf16x8 af0 = __builtin_bit_cast(bf16x8, aT[ra0*8 + (c ^ (ra0 & 7))]);
            bf16x8 af1 = __builtin_bit_cast(bf16x8, aT[ra1*8 + (c ^ (ra1 & 7))]);
            bf16x8 bg0 = __builtin_bit_cast(bf16x8, bT[rb0*8 + (c ^ (rb0 & 7))]);
            bf16x8 bg1 = __builtin_bit_cast(bf16x8, bT[rb1*8 + (c ^ (rb1 & 7))]);
            acc[0][0] = mfma16(af0, bg0, acc[0][0]);
            acc[0][1] = mfma16(af0, bg1, acc[0][1]);
            acc[1][0] = mfma16(af1, bg0, acc[1][0]);
            acc[1][1] = mfma16(af1, bg1, acc[1][1]);
        }
        if (kk + 1 < 8) __syncthreads();
    }

    #pragma unroll
    for (int ms = 0; ms < 2; ++ms)
    #pragma unroll
    for (int ns = 0; ns < 2; ++ns) {
        const int col = n0 + wn*32 + ns*16 + l16;
        const float bv = bias[col];
        const int hh = col >> 6, dk = col & 63;
        #pragma unroll
        for (int i = 0; i < 4; ++i) {
            const int m = m0 + wm*32 + ms*16 + lhi*4 + i;
            const float v = acc[ms][ns][i] + bv;
            const int b = m >> 11, s = m & 2047;
            if (mode == 0)
                dst[(((size_t)(b*CH + hh)) * CS + s) * CDK + dk] = (bf16)v;
            else
                dst[(((size_t)(b*CH + hh)) * CDK + dk) * CS + s] = (bf16)v;
        }
    }
}

// ---- output GEMM (bf16 in), 64x64 tile, gload_lds dbuf. grid (64,8,2). ----
__global__ __launch_bounds__(256) void oprojb_kernel(
    const bf16* __restrict__ Xr, const bf16* __restrict__ Xp,
    const bf16* __restrict__ Wo, const float* __restrict__ bo,
    float* __restrict__ out)
{
    __shared__ uint4 tile[2][2][512];

    const bf16* __restrict__ A = blockIdx.z ? Xp : Xr;
    float* __restrict__ dst = out + (size_t)blockIdx.z * NT;

    const int m0 = blockIdx.x * 64, n0 = blockIdx.y * 64;
    const int tid = threadIdx.x;
    const int lane = tid & 63, w = tid >> 6;
    const int wm = w >> 1, wn = w & 1;
    const int l16 = lane & 15, lhi = lane >> 4;

    const int tensor = w >> 1, half = w & 1;
    const int rlo = lane >> 3, slotL = lane & 7;
    const bf16* gbase = tensor ? Wo : A;
    const int t0 = tensor ? n0 : m0;
    const char* gp = (const char*)gbase
                   + (size_t)(t0 + half*32 + rlo) * (CD * 2)
                   + (size_t)((slotL ^ rlo) * 16);

    auto stage = [&](int buf, int kk) {
        const char* p = gp + (size_t)kk * 128;
        uint4* ld = &tile[buf][tensor][half * 256];
        #pragma unroll
        for (int i = 0; i < 4; ++i)
            gload16(p + (size_t)i * 8 * (CD * 2), ld + i * 64);
    };

    f32x4 acc[2][2] = {};

    stage(0, 0);
    asm volatile("s_waitcnt vmcnt(0)" ::: "memory");
    __syncthreads();

    for (int kk = 0; kk < 8; ++kk) {
        if (kk + 1 < 8) stage((kk + 1) & 1, kk + 1);

        const uint4* aT = &tile[kk & 1][0][0];
        const uint4* bT = &tile[kk & 1][1][0];
        #pragma unroll
        for (int ks = 0; ks < 2; ++ks) {
            const int c = ks*4 + lhi;
            const int ra0 = wm*32 + l16, ra1 = ra0 + 16;
            const int rb0 = wn*32 + l16, rb1 = rb0 + 16;
            bf16x8 af0 = __builtin_bit_cast(bf16x8, aT[ra0*8 + (c ^ (ra0 & 7))]);
            bf16x8 af1 = __builtin_bit_cast(bf16x8, aT[ra1*8 + (c ^ (ra1 & 7))]);
            bf16x8 bg0 = __builtin_bit_cast(bf16x8, bT[rb0*8 + (c ^ (rb0 & 7))]);
            bf16x8 bg1 = __builtin_bit_cast(bf16x8, bT[rb1*8 + (c ^ (rb1 & 7))]);
            acc[0][0] = mfma16(af0, bg0, acc[0][0]);
            acc[0][1] = mfma16(af0, bg1, acc[0][1]);
            acc[1][0] = mfma16(af1, bg0, acc[1][0]);
            acc[1][1] = mfma16(af1, bg1, acc[1][1]);
        }
        if (kk + 1 < 8) __syncthreads();
    }

    #pragma unroll
    for (int ms = 0; ms < 2; ++ms)
    #pragma unroll
    for (int ns = 0; ns < 2; ++ns) {
        const int col = n0 + wn*32 + ns*16 + l16;
        const float bv = bo[col];
        #pragma unroll
        for (int i = 0; i < 4; ++i) {
            const int m = m0 + wm*32 + ms*16 + lhi*4 + i;
            dst[(size_t)m * 512 + col] = acc[ms][ns][i] + bv;
        }
    }
}

// ---- flash attention (unchanged from round 6) ----
__global__ __launch_bounds__(256) void attn_kernel(
    const bf16* __restrict__ Qr, const bf16* __restrict__ Qp,
    const bf16* __restrict__ Kr, const bf16* __restrict__ Kp,
    const bf16* __restrict__ Vtr, const bf16* __restrict__ Vtp,
    const int* __restrict__ mask, int lognsp,
    float* __restrict__ POR, float* __restrict__ POP, float* __restrict__ PLs)
{
    __shared__ uint4 stg[2][4][512];   // [buf][tensor Kr,Kp,Vtr,Vtp][row*8+slot] 64KB
    __shared__ bf16 pL[4][32][64];     // per-wave P, XOR-swizzled, 16KB

    const int F = blockIdx.x;
    const int qt = (F >> 3) & 15;
    const int g  = (F & 7) | ((F >> 7) << 3);     // (bh,z) groups pinned per XCD
    const int bh = g >> lognsp, z = g & ((1 << lognsp) - 1);
    const int Lkv = CS >> lognsp, kvbase = z * Lkv;
    const int nt = Lkv >> 6;
    const int b = bh >> 3;
    const size_t base = (size_t)bh * CS * CDK;

    const int tid = threadIdx.x, lane = tid & 63, w = tid >> 6;
    const int l16 = lane & 15, lhi = lane >> 4;
    const int q0 = qt * 128 + w * 32;

    const int srowL = lane >> 3, slotL = lane & 7;
    const int chunkL = slotL ^ srowL;
    const char* gsrc;
    size_t laneoff, iStride, tStride;
    if (w == 0)      gsrc = (const char*)Kr;
    else if (w == 1) gsrc = (const char*)Kp;
    else if (w == 2) gsrc = (const char*)Vtr;
    else             gsrc = (const char*)Vtp;
    if (w < 2) {
        laneoff = base*2 + (size_t)(kvbase + srowL) * 128 + chunkL*16;
        iStride = 1024;  tStride = 8192;
    } else {
        laneoff = base*2 + (size_t)srowL * (CS*2) + (size_t)kvbase*2 + chunkL*16;
        iStride = 8 * CS * 2;  tStride = 128;
    }
    const char* gp = gsrc + laneoff;

    auto stage = [&](int bi, int t) {
        const char* p = gp + (size_t)t * tStride;
        uint4* ldst = &stg[bi][w][0];
        #pragma unroll
        for (int i = 0; i < 8; ++i)
            gload16(p + i*iStride, ldst + i*64);
    };

    stage(0, 0);   // issue first tile ASAP; prologue work below overlaps it

    bf16x8 qrf[2][2], qpf[2][2], qnf[2][2];
    #pragma unroll
    for (int ms = 0; ms < 2; ++ms)
        #pragma unroll
        for (int ks = 0; ks < 2; ++ks) {
            const size_t qoff = base + (size_t)(q0 + ms*16 + l16) * CDK + ks*32 + lhi*8;
            qrf[ms][ks] = *reinterpret_cast<const bf16x8*>(&Qr[qoff]);
            qpf[ms][ks] = *reinterpret_cast<const bf16x8*>(&Qp[qoff]);
            uint4 t = __builtin_bit_cast(uint4, qpf[ms][ks]);
            t.x ^= 0x80008000u; t.y ^= 0x80008000u; t.z ^= 0x80008000u; t.w ^= 0x80008000u;
            qnf[ms][ks] = __builtin_bit_cast(bf16x8, t);   // -qp exact
        }

    unsigned long long keep4[2] = {0ull, 0ull};
    for (int t = 0; t < nt; ++t) {
        const unsigned long long m64 =
            __ballot(mask[b*CS + kvbase + t*64 + lane] != 0);
        const unsigned long long bits = m64 >> l16;
        const unsigned long long nib =
            (bits & 1ull) | ((bits >> 15) & 2ull) | ((bits >> 30) & 4ull) | ((bits >> 45) & 8ull);
        keep4[t >> 4] |= nib << ((t & 15) * 4);
    }

    f32x4 oR[2][4] = {}, oP[2][4] = {};
    float lpart[2][4] = {};

    auto fswz = [](int r) { return (r & 7) ^ (((r >> 3) & 1) << 1); };

    asm volatile("s_waitcnt vmcnt(0)" ::: "memory");
    __syncthreads();

    for (int t = 0; t < nt; ++t) {
        if (t + 1 < nt) stage((t + 1) & 1, t + 1);

        const int bi = t & 1;
        const unsigned int k4 = (unsigned int)(keep4[t >> 4] >> ((t & 15) * 4)) & 0xFu;
        const uint4* kTr = &stg[bi][0][0];
        const uint4* kTp = &stg[bi][1][0];
        const uint4* vTr = &stg[bi][2][0];
        const uint4* vTp = &stg[bi][3][0];

        float sc[2][4][4];
        #pragma unroll
        for (int kb = 0; kb < 4; ++kb) {
            const int krow = kb*16 + l16;
            bf16x8 kr8[2], kp8[2];
            #pragma unroll
            for (int ks = 0; ks < 2; ++ks) {
                const int ci = krow*8 + ((ks*4 + lhi) ^ (krow & 7));
                kr8[ks] = __builtin_bit_cast(bf16x8, kTr[ci]);
                kp8[ks] = __builtin_bit_cast(bf16x8, kTp[ci]);
            }
            const unsigned int keep = (k4 >> kb) & 1u;
            #pragma unroll
            for (int ms = 0; ms < 2; ++ms) {
                f32x4 aR = {}, aP = {};
                __builtin_amdgcn_s_setprio(1);
                #pragma unroll
                for (int ks = 0; ks < 2; ++ks) {
                    aR = mfma16(qrf[ms][ks], kr8[ks], aR);
                    aR = mfma16(qnf[ms][ks], kp8[ks], aR);
                    aP = mfma16(qrf[ms][ks], kp8[ks], aP);
                    aP = mfma16(qpf[ms][ks], kr8[ks], aP);
                }
                __builtin_amdgcn_s_setprio(0);
                #pragma unroll
                for (int i = 0; i < 4; ++i) {
                    const float sr = aR[i], sp = aP[i];
                    const float mag = __builtin_amdgcn_sqrtf(fmaf(sr, sr, sp*sp));
                    float p = __builtin_amdgcn_exp2f(fmaf(mag, 0.18033688f, -5.77078016f));
                    p = keep ? p : 0.0f;
                    sc[ms][kb][i] = p;
                    lpart[ms][i] += p;
                }
            }
        }

        bf16* pB = &pL[w][0][0];
        #pragma unroll
        for (int ms = 0; ms < 2; ++ms)
            #pragma unroll
            for (int i = 0; i < 4; ++i) {
                const int row = ms*16 + lhi*4 + i;
                const int sw = fswz(row) << 3;
                #pragma unroll
                for (int kb = 0; kb < 4; ++kb)
                    pB[row*64 + ((kb*16 + l16) ^ sw)] = (bf16)sc[ms][kb][i];
            }
        asm volatile("s_waitcnt lgkmcnt(0)" ::: "memory");
        __builtin_amdgcn_sched_barrier(0);

        const uint4* pW = reinterpret_cast<const uint4*>(&pL[w][0][0]);
        #pragma unroll
        for (int ks = 0; ks < 2; ++ks) {
            bf16x8 pf[2];
            #pragma unroll
            for (int ms = 0; ms < 2; ++ms) {
                const int prow = ms*16 + l16;
                pf[ms] = __builtin_bit_cast(bf16x8, pW[prow*8 + ((ks*4 + lhi) ^ fswz(prow))]);
            }
            __builtin_amdgcn_s_setprio(1);
            #pragma unroll
            for (int d = 0; d < 4; ++d) {
                const int vrow = d*16 + l16;
                const int ci = vrow*8 + ((ks*4 + lhi) ^ (vrow & 7));
                const bf16x8 v8r = __builtin_bit_cast(bf16x8, vTr[ci]);
                const bf16x8 v8p = __builtin_bit_cast(bf16x8, vTp[ci]);
                #pragma unroll
                for (int ms = 0; ms < 2; ++ms) {
                    oR[ms][d] = mfma16(pf[ms], v8r, oR[ms][d]);
                    oP[ms][d] = mfma16(pf[ms], v8p, oP[ms][d]);
                }
            }
            __builtin_amdgcn_s_setprio(0);
        }

        if (t + 1 < nt) __syncthreads();
    }

    #pragma unroll
    for (int ms = 0; ms < 2; ++ms)
        #pragma unroll
        for (int i = 0; i < 4; ++i) {
            float v = lpart[ms][i];
            v += __shfl_xor(v, 1); v += __shfl_xor(v, 2);
            v += __shfl_xor(v, 4); v += __shfl_xor(v, 8);
            lpart[ms][i] = v;
        }
    const int r0 = bh * CS + q0;
    if (l16 == 0) {
        #pragma unroll
        for (int ms = 0; ms < 2; ++ms)
            #pragma unroll
            for (int i = 0; i < 4; ++i)
                PLs[(size_t)z * NROWS + r0 + ms*16 + lhi*4 + i] = lpart[ms][i];
    }
    const size_t zo = (size_t)z * NROWS * 64;
    #pragma unroll
    for (int ms = 0; ms < 2; ++ms)
        #pragma unroll
        for (int d = 0; d < 4; ++d) {
            const int col = d*16 + l16;
            #pragma unroll
            for (int i = 0; i < 4; ++i) {
                const size_t off = zo + (size_t)(r0 + ms*16 + lhi*4 + i) * 64 + col;
                POR[off] = oR[ms][d][i];
                POP[off] = oP[ms][d][i];
            }
        }
}

// ---- combine KV-split partials, normalize, write [B,S,D] bf16 (x4 vectorized) ----
__global__ __launch_bounds__(256) void merge_kernel(
    const float* __restrict__ POR, const float* __restrict__ POP,
    const float* __restrict__ PLs, int nsp,
    bf16* __restrict__ Xr, bf16* __restrict__ Xp)
{
    const int idx = blockIdx.x * 256 + threadIdx.x;   // 0 .. NROWS*16-1
    const int r = idx >> 4, c0 = (idx & 15) * 4;
    float l = 0.f;
    f32x4 orv = {}, opv = {};
    for (int zz = 0; zz < nsp; ++zz) {
        l += PLs[(size_t)zz * NROWS + r];
        const size_t o = (size_t)zz * NROWS * 64 + (size_t)r * 64 + c0;
        orv += *reinterpret_cast<const f32x4*>(&POR[o]);
        opv += *reinterpret_cast<const f32x4*>(&POP[o]);
    }
    const float inv = 1.f / l;
    const int bh = r >> 11, q = r & 2047;
    const int b = bh >> 3, h = bh & 7;
    const size_t off = ((size_t)(b*CS + q)) * CD + h*CDK + c0;
    bf16 vr[4], vp[4];
    #pragma unroll
    for (int j = 0; j < 4; ++j) { vr[j] = (bf16)(orv[j]*inv); vp[j] = (bf16)(opv[j]*inv); }
    *reinterpret_cast<uint2*>(&Xr[off]) = *reinterpret_cast<const uint2*>(vr);
    *reinterpret_cast<uint2*>(&Xp[off]) = *reinterpret_cast<const uint2*>(vp);
}

extern "C" void kernel_launch(void* const* d_in, const int* in_sizes, int n_in,
                              void* d_out, int out_size, void* d_ws, size_t ws_size,
                              hipStream_t stream) {
    const float* q_r = (const float*)d_in[0];
    const float* k_r = (const float*)d_in[1];
    const float* v_r = (const float*)d_in[2];
    const float* q_p = (const float*)d_in[3];
    const float* k_p = (const float*)d_in[4];
    const float* v_p = (const float*)d_in[5];
    const int*  mask = (const int*)d_in[6];
    const float* Wq = (const float*)d_in[7];  const float* bq = (const float*)d_in[8];
    const float* Wk = (const float*)d_in[9];  const float* bk = (const float*)d_in[10];
    const float* Wv = (const float*)d_in[11]; const float* bv = (const float*)d_in[12];
    const float* Wo = (const float*)d_in[13]; const float* bo = (const float*)d_in[14];
    float* out = (float*)d_out;

    bf16* ws = (bf16*)d_ws;
    bf16* Abf = ws;                          // 6 * NT
    bf16* Wbf = ws + 6 * NT;                 // 4 * WN
    bf16* Qr  = Wbf + 4 * WN;
    bf16 *Qp = Qr + NT, *Kr = Qp + NT, *Kp = Kr + NT;
    bf16 *Vtr = Kp + NT, *Vtp = Vtr + NT;
    bf16 *Xr = Vtp + NT, *Xp = Xr + NT;
    float* POR = (float*)(Xp + NT);

    const size_t fixedB = (14 * NT + 4 * WN) * sizeof(bf16);
    const size_t per_split = (size_t)NROWS * 64 * 4 * 2 + (size_t)NROWS * 4;
    int nsp, lognsp;
    if (ws_size >= fixedB + 2 * per_split) { nsp = 2; lognsp = 1; }
    else                                   { nsp = 1; lognsp = 0; }
    float* POP = POR + (size_t)nsp * NROWS * 64;
    float* PLs = POP + (size_t)nsp * NROWS * 64;

    dim3 blk(256);

    // conversion pass
    CvtP C;
    C.src[0]=q_r; C.src[1]=q_p; C.src[2]=k_r; C.src[3]=k_p; C.src[4]=v_r; C.src[5]=v_p;
    C.src[6]=Wq;  C.src[7]=Wk;  C.src[8]=Wv;  C.src[9]=Wo;
    for (int i = 0; i < 6; ++i) { C.dst[i] = Abf + (size_t)i * NT; C.n8[i] = (int)(NT / 8); }
    for (int i = 0; i < 4; ++i) { C.dst[6+i] = Wbf + (size_t)i * WN; C.n8[6+i] = (int)(WN / 8); }
    cvt_kernel<<<dim3((unsigned)(NT / 8 / 256), 10), blk, 0, stream>>>(C);

    // projections
    PB P;
    for (int i = 0; i < 6; ++i) P.A[i] = Abf + (size_t)i * NT;
    P.W[0]=Wbf;      P.W[1]=Wbf;      P.W[2]=Wbf+WN;   P.W[3]=Wbf+WN;
    P.W[4]=Wbf+2*WN; P.W[5]=Wbf+2*WN;
    P.bias[0]=bq; P.bias[1]=bq; P.bias[2]=bk; P.bias[3]=bk; P.bias[4]=bv; P.bias[5]=bv;
    P.dst[0]=Qr; P.dst[1]=Qp; P.dst[2]=Kr; P.dst[3]=Kp; P.dst[4]=Vtr; P.dst[5]=Vtp;
    P.mode[0]=0; P.mode[1]=0; P.mode[2]=0; P.mode[3]=0; P.mode[4]=1; P.mode[5]=1;
    projb_kernel<<<dim3(64, 8, 6), blk, 0, stream>>>(P);

    attn_kernel<<<dim3(256 * nsp), blk, 0, stream>>>(Qr, Qp, Kr, Kp, Vtr, Vtp,
                                                     mask, lognsp, POR, POP, PLs);

    merge_kernel<<<dim3(NROWS * 16 / 256), blk, 0, stream>>>(POR, POP, PLs, nsp, Xr, Xp);

    oprojb_kernel<<<dim3(64, 8, 2), blk, 0, stream>>>(Xr, Xp, Wbf + 3 * WN, bo, out);
}